// Round 1
// baseline (309.087 us; speedup 1.0000x reference)
//
#include <hip/hip_runtime.h>

// Problem constants (static per reference): x shape (B, C, H, W) fp32
#define B   64
#define C   2048
#define H   24
#define W   12
#define S   (H * W)        // 288 spatial positions per (b, c)
#define S4  (S / 4)        // 72 float4 per channel slice
#define NCH 32             // channel chunks
#define CCH (C / NCH)      // 64 channels per chunk
#define RH  8              // round(0.33 * 24)

// ---------------------------------------------------------------------------
// Kernel A: contiguous float4 copy x->out + per-(b,chunk) spatial energy sums.
// Block = 288 threads. Thread t maps to byte offset 16*t within the chunk:
//   f = t % 72 (float4 column in a slice), g = t / 72 (one of 4 c-subgroups).
// Each iteration of the c-loop the block touches one contiguous 4608B span ->
// perfect 16B/lane coalescing for both load and store.
// Thread t's 4 accumulated spatial positions (4f..4f+3) are FIXED across the
// loop -> pure register accumulation, no LDS atomics.
// ---------------------------------------------------------------------------
__global__ __launch_bounds__(288) void k_energy_copy(const float* __restrict__ x,
                                                     float* __restrict__ out,
                                                     float* __restrict__ part) {
    const int chunk = blockIdx.x;   // 0..NCH-1
    const int b     = blockIdx.y;   // 0..B-1
    const int t     = threadIdx.x;  // 0..287
    const int f     = t % S4;       // float4 col within slice
    const int g     = t / S4;       // 0..3 channel subgroup

    const size_t base4 = (size_t)b * C * S4 + (size_t)chunk * CCH * S4;
    const float4* __restrict__ x4 = (const float4*)x + base4;
    float4* __restrict__       o4 = (float4*)out + base4;

    float4 acc = {0.f, 0.f, 0.f, 0.f};
    #pragma unroll 4
    for (int c = g; c < CCH; c += 4) {
        float4 v = x4[c * S4 + f];
        o4[c * S4 + f] = v;
        acc.x += v.x * v.x;
        acc.y += v.y * v.y;
        acc.z += v.z * v.z;
        acc.w += v.w * v.w;
    }

    // Reduce the 4 c-subgroups' partials for each spatial position.
    __shared__ float4 sm4[4][S4];   // 4 * 288 floats = 4.6 KB
    sm4[g][f] = acc;
    __syncthreads();

    const float* sm = (const float*)sm4;
    // thread t owns spatial position s = t (288 threads cover all 288)
    float sum = sm[0 * S + t] + sm[1 * S + t] + sm[2 * S + t] + sm[3 * S + t];
    part[((size_t)b * NCH + chunk) * S + t] = sum;
}

// ---------------------------------------------------------------------------
// Kernel B: per sample — reduce 32 chunk partials -> act[288], row-max over W,
// then mark the top-RH rows (stable-argsort tie semantics: on equal values the
// LARGER index wins a top slot, matching argsort(ascending)[-RH:]).
// ---------------------------------------------------------------------------
__global__ __launch_bounds__(288) void k_select(const float* __restrict__ part,
                                                int* __restrict__ drop) {
    const int b = blockIdx.x;
    const int t = threadIdx.x;  // 0..287

    __shared__ float act[S];
    __shared__ float rm[H];

    const float* p = part + (size_t)b * NCH * S + t;
    float sum = 0.f;
    #pragma unroll
    for (int ch = 0; ch < NCH; ch++) sum += p[(size_t)ch * S];
    act[t] = sum;
    __syncthreads();

    if (t < H) {
        float m = act[t * W];
        #pragma unroll
        for (int w = 1; w < W; w++) m = fmaxf(m, act[t * W + w]);
        rm[t] = m;
    }
    __syncthreads();

    if (t < H) {
        const float mt = rm[t];
        int cnt = 0;
        #pragma unroll
        for (int j = 0; j < H; j++) {
            float mj = rm[j];
            if (mj > mt || (mj == mt && j > t)) cnt++;
        }
        drop[b * H + t] = (cnt < RH) ? 1 : 0;
    }
}

// ---------------------------------------------------------------------------
// Kernel C: zero the dropped rows of out. One block per (b, h); non-dropped
// rows exit immediately. float4 stores: 3 float4 per (c) slice (W=12 floats),
// 6144 float4 per active block. These lines were written by kernel A moments
// ago -> expected to be dirty in L2/L3, so the overwrite is mostly absorbed.
// ---------------------------------------------------------------------------
__global__ __launch_bounds__(256) void k_zero(float* __restrict__ out,
                                              const int* __restrict__ drop) {
    const int h = blockIdx.x;
    const int b = blockIdx.y;
    if (!drop[b * H + h]) return;

    float4* __restrict__ o4 = (float4*)out + (size_t)b * C * S4 + h * (W / 4);
    const float4 z = {0.f, 0.f, 0.f, 0.f};
    for (int i = threadIdx.x; i < C * (W / 4); i += 256) {
        int c = i / 3;
        int q = i - c * 3;
        o4[(size_t)c * S4 + q] = z;
    }
}

extern "C" void kernel_launch(void* const* d_in, const int* in_sizes, int n_in,
                              void* d_out, int out_size, void* d_ws, size_t ws_size,
                              hipStream_t stream) {
    const float* x   = (const float*)d_in[0];
    float*       out = (float*)d_out;

    // ws layout: [ partials: B*NCH*S floats = 2.36 MB ][ drop: B*H ints = 6 KB ]
    float* part = (float*)d_ws;
    int*   drop = (int*)((char*)d_ws + (size_t)B * NCH * S * sizeof(float));

    k_energy_copy<<<dim3(NCH, B), 288, 0, stream>>>(x, out, part);
    k_select<<<B, 288, 0, stream>>>(part, drop);
    k_zero<<<dim3(H, B), 256, 0, stream>>>(out, drop);
}

// Round 3
// 278.270 us; speedup vs baseline: 1.1107x; 1.1107x over previous
//
#include <hip/hip_runtime.h>

// Problem constants (static per reference): x shape (B, C, H, W) fp32
#define B   64
#define C   2048
#define H   24
#define W   12
#define S   (H * W)        // 288 spatial positions per (b, c)
#define S4  (S / 4)        // 72 float4 per channel slice
#define W4  (W / 4)        // 3 float4 per row
#define NCH 32             // channel chunks
#define CCH (C / NCH)      // 64 channels per chunk
#define RH  8              // round(0.33 * 24)

// Native clang vector type — required by __builtin_nontemporal_store
// (HIP's float4 is a struct wrapper it rejects). Lowers to dwordx4 ops.
typedef float f4 __attribute__((ext_vector_type(4)));

// ---------------------------------------------------------------------------
// Kernel 1: read-only energy pass. Block (chunk, b), 288 threads.
// Thread t, iteration k accesses float4 index t + 288k within the chunk's
// 4608-float4 span -> the block walks contiguous 4.6 KB spans, perfectly
// coalesced. Thread t's 4 spatial positions are fixed -> register accumulate.
// Side effect: x ends up resident in L3 (144 MiB < 256 MiB) for kernel 3.
// ---------------------------------------------------------------------------
__global__ __launch_bounds__(288) void k_energy(const float* __restrict__ x,
                                                float* __restrict__ part) {
    const int chunk = blockIdx.x;   // 0..NCH-1
    const int b     = blockIdx.y;   // 0..B-1
    const int t     = threadIdx.x;  // 0..287
    const int f     = t % S4;
    const int g     = t / S4;

    const f4* __restrict__ x4 =
        (const f4*)x + (size_t)(b * C + chunk * CCH) * S4;

    f4 acc = {0.f, 0.f, 0.f, 0.f};
    #pragma unroll
    for (int k = 0; k < CCH / 4; ++k) {
        f4 v = x4[t + S * k];
        acc += v * v;
    }

    __shared__ f4 sm4[4][S4];   // 4.6 KB
    sm4[g][f] = acc;
    __syncthreads();

    const float* sm = (const float*)sm4;
    // thread t owns spatial position t (t < 288 == S)
    part[((size_t)b * NCH + chunk) * S + t] =
        sm[0 * S + t] + sm[1 * S + t] + sm[2 * S + t] + sm[3 * S + t];
}

// ---------------------------------------------------------------------------
// Kernel 2: per sample — reduce 32 chunk partials -> act[288], row-max over W,
// mark top-RH rows. Tie semantics match stable argsort(ascending)[-RH:]:
// on equal values the larger index wins a top slot. (absmax 0.0 in round 1.)
// ---------------------------------------------------------------------------
__global__ __launch_bounds__(288) void k_select(const float* __restrict__ part,
                                                int* __restrict__ drop) {
    const int b = blockIdx.x;
    const int t = threadIdx.x;  // 0..287

    __shared__ float act[S];
    __shared__ float rm[H];

    const float* p = part + (size_t)b * NCH * S + t;
    float sum = 0.f;
    #pragma unroll
    for (int ch = 0; ch < NCH; ch++) sum += p[(size_t)ch * S];
    act[t] = sum;
    __syncthreads();

    if (t < H) {
        float m = act[t * W];
        #pragma unroll
        for (int w = 1; w < W; w++) m = fmaxf(m, act[t * W + w]);
        rm[t] = m;
    }
    __syncthreads();

    if (t < H) {
        const float mt = rm[t];
        int cnt = 0;
        #pragma unroll
        for (int j = 0; j < H; j++) {
            float mj = rm[j];
            if (mj > mt || (mj == mt && j > t)) cnt++;
        }
        drop[b * H + t] = (cnt < RH) ? 1 : 0;
    }
}

// ---------------------------------------------------------------------------
// Kernel 3: masked copy x -> out. Same (chunk, b) x 288 geometry as kernel 1.
// Since idx = t + 288k and 288 % 72 == 0, the spatial row h = (t%72)/3 is
// CONSTANT per thread -> one mask load before the loop; hot loop is pure
// load -> cndmask -> nontemporal store, fully contiguous both directions.
// x reads mostly hit L3 (kernel 1 warmed it); nontemporal stores keep out
// from evicting x mid-kernel.
// ---------------------------------------------------------------------------
__global__ __launch_bounds__(288) void k_mask_copy(const float* __restrict__ x,
                                                   float* __restrict__ out,
                                                   const int* __restrict__ drop) {
    const int chunk = blockIdx.x;
    const int b     = blockIdx.y;
    const int t     = threadIdx.x;
    const int h     = (t % S4) / W4;
    const float keep = (drop[b * H + h] == 0) ? 1.0f : 0.0f;

    const size_t base4 = (size_t)(b * C + chunk * CCH) * S4;
    const f4* __restrict__ x4 = (const f4*)x + base4;
    f4* __restrict__       o4 = (f4*)out + base4;

    #pragma unroll
    for (int k = 0; k < CCH / 4; ++k) {
        f4 v = x4[t + S * k];
        f4 r = v * keep;   // keep is 1.0 or 0.0; 0*x==0 exactly (inputs finite)
        __builtin_nontemporal_store(r, &o4[t + S * k]);
    }
}

extern "C" void kernel_launch(void* const* d_in, const int* in_sizes, int n_in,
                              void* d_out, int out_size, void* d_ws, size_t ws_size,
                              hipStream_t stream) {
    const float* x   = (const float*)d_in[0];
    float*       out = (float*)d_out;

    // ws layout: [ partials: B*NCH*S floats = 2.36 MB ][ drop: B*H ints = 6 KB ]
    float* part = (float*)d_ws;
    int*   drop = (int*)((char*)d_ws + (size_t)B * NCH * S * sizeof(float));

    k_energy<<<dim3(NCH, B), 288, 0, stream>>>(x, part);
    k_select<<<B, 288, 0, stream>>>(part, drop);
    k_mask_copy<<<dim3(NCH, B), 288, 0, stream>>>(x, out, drop);
}